// Round 1
// baseline (404.357 us; speedup 1.0000x reference)
//
#include <hip/hip_runtime.h>

#define N 8192
#define C 64
#define S 16

static constexpr float BN_INV = 0.9999950000374997f; // 1/sqrt(1+1e-5)
static constexpr float LN_EPS = 1e-5f;

// ---------------------------------------------------------------------------
// K1: xq/xk/xv = feats @ W{q,k,v} + b  (8192x64 @ 64x64, f32)
// 256 blocks x 256 thr; 32 rows/block; W and feats tile staged in LDS (56KB)
// ---------------------------------------------------------------------------
__global__ __launch_bounds__(256) void qkv_kernel(
    const float* __restrict__ feats,
    const float* __restrict__ Wq, const float* __restrict__ bq,
    const float* __restrict__ Wk, const float* __restrict__ bk,
    const float* __restrict__ Wv, const float* __restrict__ bv,
    float* __restrict__ xq, float* __restrict__ xk, float* __restrict__ xv)
{
    __shared__ float sF[32 * 64];
    __shared__ float sW[3 * 64 * 64];
    const int t = threadIdx.x;
    const int row0 = blockIdx.x * 32;
    {
        const float4* src = (const float4*)(feats + row0 * 64);
        float4* dst = (float4*)sF;
        dst[t] = src[t];
        dst[t + 256] = src[t + 256];
        const float4* wq4 = (const float4*)Wq;
        const float4* wk4 = (const float4*)Wk;
        const float4* wv4 = (const float4*)Wv;
        float4* d0 = (float4*)sW;
        float4* d1 = (float4*)(sW + 4096);
        float4* d2 = (float4*)(sW + 8192);
#pragma unroll
        for (int k = 0; k < 4; k++) {
            d0[t + k * 256] = wq4[t + k * 256];
            d1[t + k * 256] = wk4[t + k * 256];
            d2[t + k * 256] = wv4[t + k * 256];
        }
    }
    __syncthreads();
    const int col = t & 63, rg = t >> 6;
    const float* biases[3] = {bq, bk, bv};
    float* outs[3] = {xq, xk, xv};
    for (int m = 0; m < 3; m++) {
        const float* w = sW + m * 4096;
        float bias = biases[m][col];
        float acc[8];
#pragma unroll
        for (int k = 0; k < 8; k++) acc[k] = bias;
        for (int c = 0; c < 64; c++) {
            float wv = w[c * 64 + col];
#pragma unroll
            for (int k = 0; k < 8; k++)
                acc[k] = fmaf(sF[(rg * 8 + k) * 64 + c], wv, acc[k]);
        }
        float* o = outs[m] + row0 * 64;
#pragma unroll
        for (int k = 0; k < 8; k++) o[(rg * 8 + k) * 64 + col] = acc[k];
    }
}

// ---------------------------------------------------------------------------
// K2: exact 16-NN by (d2, idx) ascending == jax.lax.top_k(-d2, 16) order.
// key = (d2 << 13) | idx fits 30 bits (d2 <= 3*127^2 < 2^17, idx < 2^13).
// 512 blocks x 256 thr: 16 queries/block x 16 partitions. Each lane scans 512
// interleaved candidates keeping sorted top-16; 16-lane shuffle tournament
// merges partitions in ascending order.
// ---------------------------------------------------------------------------
__global__ __launch_bounds__(256) void knn_kernel(
    const int4* __restrict__ idx4, int* __restrict__ knn_out)
{
    __shared__ int4 tile[512];
    const int t = threadIdx.x;
    const int p = t & 15, qi = t >> 4;
    const int q = blockIdx.x * 16 + qi;
    const int4 qc = idx4[q];
    const int qx = qc.y, qy = qc.z, qz = qc.w;
    unsigned a[16];
#pragma unroll
    for (int i = 0; i < 16; i++) a[i] = 0xFFFFFFFFu;

    for (int tb = 0; tb < 16; ++tb) {
        __syncthreads();
        tile[t] = idx4[tb * 512 + t];
        tile[t + 256] = idx4[tb * 512 + 256 + t];
        __syncthreads();
#pragma unroll 2
        for (int i = 0; i < 32; ++i) {
            int4 cd = tile[i * 16 + p];
            int j = tb * 512 + i * 16 + p;
            int dx = cd.y - qx, dy = cd.z - qy, dz = cd.w - qz;
            int d2 = dx * dx + dy * dy + dz * dz;
            unsigned key = ((unsigned)d2 << 13) | (unsigned)j;
            if (key < a[15]) {
                a[15] = key;
#pragma unroll
                for (int k = 15; k > 0; --k) {
                    unsigned lo = min(a[k - 1], a[k]);
                    unsigned hi = a[k - 1] ^ a[k] ^ lo;
                    a[k - 1] = lo;
                    a[k] = hi;
                }
            }
        }
    }
    // tournament merge of the 16 partition lists (within each 16-lane group)
    for (int r = 0; r < 16; ++r) {
        unsigned m = a[0];
        m = min(m, (unsigned)__shfl_xor((int)m, 1, 16));
        m = min(m, (unsigned)__shfl_xor((int)m, 2, 16));
        m = min(m, (unsigned)__shfl_xor((int)m, 4, 16));
        m = min(m, (unsigned)__shfl_xor((int)m, 8, 16));
        if (p == r) knn_out[q * 16 + r] = (int)(m & 8191u);
        if (a[0] == m) { // unique key -> exactly one winner pops
#pragma unroll
            for (int k = 0; k < 15; ++k) a[k] = a[k + 1];
            a[15] = 0xFFFFFFFFu;
        }
    }
}

// ---------------------------------------------------------------------------
// K3: fused vector-attention. 2048 blocks x 512 thr, 4 queries/block.
// LDS (~143KB): Ww1, Ww2, Wp2 + padded per-query tiles (strides 68/132/17
// chosen to break 8-way bank conflicts on broadcast reads).
// ---------------------------------------------------------------------------
__global__ __launch_bounds__(512) void attn_kernel(
    const int4* __restrict__ idx4, const int* __restrict__ knn,
    const float* __restrict__ xq, const float* __restrict__ xk,
    const float* __restrict__ xv,
    const float* __restrict__ Wp1, const float* __restrict__ pg,
    const float* __restrict__ pb, const float* __restrict__ Wp2,
    const float* __restrict__ bp2,
    const float* __restrict__ wg1, const float* __restrict__ wb1,
    const float* __restrict__ Ww1,
    const float* __restrict__ wg2, const float* __restrict__ wb2,
    const float* __restrict__ Ww2, const float* __restrict__ bw2,
    float* __restrict__ attn)
{
    __shared__ float sW1[64 * 128];   // 32KB
    __shared__ float sW2[128 * 64];   // 32KB
    __shared__ float sWp2[16 * 64];   // 4KB
    __shared__ float su[4][16 * 68];  // relu(bn1(w0)), later reused for logits
    __shared__ float sv[4][16 * 68];  // x_v + p_r
    __shared__ float so1[4][16 * 132];
    __shared__ float sph[4][16 * 17];
    __shared__ float sp[4][16][4];
    __shared__ int sj[4][16];
    __shared__ float sg1[64], sb1[64], sg2[128], sb2[128], sbw2[64], sbp2[64];
    __shared__ float sWp1[48], spg[16], spb[16];

    const int t = threadIdx.x;
    const int q0 = blockIdx.x * 4;
    {
        const float4* s1 = (const float4*)Ww1;
        const float4* s2 = (const float4*)Ww2;
        float4* d1 = (float4*)sW1;
        float4* d2 = (float4*)sW2;
#pragma unroll
        for (int k = 0; k < 4; k++) {
            d1[t + k * 512] = s1[t + k * 512];
            d2[t + k * 512] = s2[t + k * 512];
        }
        if (t < 256) ((float4*)sWp2)[t] = ((const float4*)Wp2)[t];
        if (t < 128) { sg2[t] = wg2[t] * BN_INV; sb2[t] = wb2[t]; }
        if (t < 64) {
            sg1[t] = wg1[t] * BN_INV; sb1[t] = wb1[t];
            sbw2[t] = bw2[t]; sbp2[t] = bp2[t];
        }
        if (t < 48) sWp1[t] = Wp1[t];
        if (t < 16) { spg[t] = pg[t] * BN_INV; spb[t] = pb[t]; }
    }
    if (t < 64) {
        int ql = t >> 4, s = t & 15, q = q0 + ql;
        int j = knn[q * 16 + s];
        sj[ql][s] = j;
        int4 pc = idx4[j];
        int4 qc = idx4[q];
        sp[ql][s][0] = (float)(pc.y - qc.y);
        sp[ql][s][1] = (float)(pc.z - qc.z);
        sp[ql][s][2] = (float)(pc.w - qc.w);
    }
    __syncthreads();
    // p-MLP hidden: ph = relu(bn(p @ Wp1))
#pragma unroll
    for (int e = t; e < 1024; e += 512) {
        int ql = e >> 8, s = (e >> 4) & 15, h = e & 15;
        float x = sp[ql][s][0] * sWp1[h] + sp[ql][s][1] * sWp1[16 + h] +
                  sp[ql][s][2] * sWp1[32 + h];
        x = x * spg[h] + spb[h];
        sph[ql][s * 17 + h] = fmaxf(x, 0.f);
    }
    __syncthreads();
    // u = relu(bn1(xk - xq + p_r)), v = xv + p_r
    {
        int ql = t >> 7, s = (t >> 3) & 15, c0 = (t & 7) * 8;
        int q = q0 + ql, j = sj[ql][s];
        float pr[8];
#pragma unroll
        for (int i = 0; i < 8; i++) pr[i] = sbp2[c0 + i];
        const float* ph = &sph[ql][s * 17];
#pragma unroll
        for (int h = 0; h < 16; h++) {
            float pv = ph[h];
#pragma unroll
            for (int i = 0; i < 8; i++)
                pr[i] = fmaf(pv, sWp2[h * 64 + c0 + i], pr[i]);
        }
        const float4* k4 = (const float4*)(xk + j * 64 + c0);
        const float4* v4 = (const float4*)(xv + j * 64 + c0);
        const float4* q4 = (const float4*)(xq + q * 64 + c0);
        float4 ka = k4[0], kb = k4[1], va = v4[0], vb = v4[1];
        float4 qa = q4[0], qb = q4[1];
        float kk[8] = {ka.x, ka.y, ka.z, ka.w, kb.x, kb.y, kb.z, kb.w};
        float vv[8] = {va.x, va.y, va.z, va.w, vb.x, vb.y, vb.z, vb.w};
        float qq[8] = {qa.x, qa.y, qa.z, qa.w, qb.x, qb.y, qb.z, qb.w};
        float* urow = &su[ql][s * 68];
        float* vrow = &sv[ql][s * 68];
#pragma unroll
        for (int i = 0; i < 8; i++) {
            float w0 = kk[i] - qq[i] + pr[i];
            urow[c0 + i] = fmaxf(w0 * sg1[c0 + i] + sb1[c0 + i], 0.f);
            vrow[c0 + i] = vv[i] + pr[i];
        }
    }
    __syncthreads();
    // GEMM1: o1 = relu(bn2(u @ Ww1)); thread outputs o = ob + 32*i + k
    {
        int ql = t >> 7, s = (t >> 3) & 15, ob = (t & 7) * 4;
        float acc[16];
#pragma unroll
        for (int i = 0; i < 16; i++) acc[i] = 0.f;
        const float* u = &su[ql][s * 68];
        for (int c = 0; c < 64; c++) {
            float uv = u[c];
#pragma unroll
            for (int i = 0; i < 4; i++) {
                const float* wr = &sW1[c * 128 + ob + 32 * i];
#pragma unroll
                for (int k = 0; k < 4; k++)
                    acc[i * 4 + k] = fmaf(uv, wr[k], acc[i * 4 + k]);
            }
        }
        float* orow = &so1[ql][s * 132];
#pragma unroll
        for (int i = 0; i < 4; i++)
#pragma unroll
            for (int k = 0; k < 4; k++) {
                int o = ob + 32 * i + k;
                orow[o] = fmaxf(acc[i * 4 + k] * sg2[o] + sb2[o], 0.f);
            }
    }
    __syncthreads();
    // GEMM2: logits = o1 @ Ww2 + bw2 (into su, reused)
    {
        int ql = t >> 7, s = (t >> 3) & 15, o0 = (t & 7) * 8;
        float acc[8];
#pragma unroll
        for (int i = 0; i < 8; i++) acc[i] = 0.f;
        const float* orow = &so1[ql][s * 132];
        for (int c = 0; c < 128; c++) {
            float ov = orow[c];
#pragma unroll
            for (int i = 0; i < 8; i++)
                acc[i] = fmaf(ov, sW2[c * 64 + o0 + i], acc[i]);
        }
        float* lrow = &su[ql][s * 68];
#pragma unroll
        for (int i = 0; i < 8; i++) lrow[o0 + i] = acc[i] + sbw2[o0 + i];
    }
    __syncthreads();
    // softmax over s (per channel) + einsum
    if (t < 256) {
        int ql = t >> 6, c = t & 63, q = q0 + ql;
        float mx = -1e30f;
#pragma unroll
        for (int s = 0; s < 16; s++) mx = fmaxf(mx, su[ql][s * 68 + c]);
        float e[16], sum = 0.f;
#pragma unroll
        for (int s = 0; s < 16; s++) {
            e[s] = expf(su[ql][s * 68 + c] - mx);
            sum += e[s];
        }
        float inv = 1.f / sum;
        float acc = 0.f;
#pragma unroll
        for (int s = 0; s < 16; s++) acc = fmaf(sv[ql][s * 68 + c], e[s], acc);
        attn[q * 64 + c] = acc * inv;
    }
}

// ---------------------------------------------------------------------------
// K4a: h2 = relu(bn(relu(bn([feats,attn] @ Wc1)) @ Wc2)); 512 blocks x 256 thr
// ---------------------------------------------------------------------------
__global__ __launch_bounds__(256) void head1_kernel(
    const float* __restrict__ feats, const float* __restrict__ attn,
    const float* __restrict__ Wc1, const float* __restrict__ cg1,
    const float* __restrict__ cb1, const float* __restrict__ Wc2,
    const float* __restrict__ cg2, const float* __restrict__ cb2,
    float* __restrict__ h2out)
{
    __shared__ float sWa[128 * 128];
    __shared__ float sWb[128 * 128];
    __shared__ float sh[16 * 132];
    __shared__ float sh1[16 * 132];
    __shared__ float sga[128], sba[128], sgb[128], sbb[128];
    const int t = threadIdx.x;
    const int row0 = blockIdx.x * 16;
    {
        const float4* a4 = (const float4*)Wc1;
        const float4* b4 = (const float4*)Wc2;
        float4* da = (float4*)sWa;
        float4* db = (float4*)sWb;
#pragma unroll
        for (int k = 0; k < 16; k++) {
            da[t + k * 256] = a4[t + k * 256];
            db[t + k * 256] = b4[t + k * 256];
        }
        if (t < 128) {
            sga[t] = cg1[t] * BN_INV; sba[t] = cb1[t];
            sgb[t] = cg2[t] * BN_INV; sbb[t] = cb2[t];
        }
    }
#pragma unroll
    for (int k = 0; k < 8; k++) {
        int e = t + k * 256;
        int r = e >> 7, c = e & 127;
        float xval = (c < 64) ? feats[(row0 + r) * 64 + c]
                              : attn[(row0 + r) * 64 + (c - 64)];
        sh[r * 132 + c] = xval;
    }
    __syncthreads();
    const int r = t >> 4, ob = (t & 15) * 4; // o = ob + 64*i + k
    {
        float acc[8];
#pragma unroll
        for (int i = 0; i < 8; i++) acc[i] = 0.f;
        const float* hrow = &sh[r * 132];
        for (int c = 0; c < 128; c++) {
            float hv = hrow[c];
#pragma unroll
            for (int i = 0; i < 2; i++) {
                const float* wr = &sWa[c * 128 + ob + 64 * i];
#pragma unroll
                for (int k = 0; k < 4; k++)
                    acc[i * 4 + k] = fmaf(hv, wr[k], acc[i * 4 + k]);
            }
        }
        float* h1row = &sh1[r * 132];
#pragma unroll
        for (int i = 0; i < 2; i++)
#pragma unroll
            for (int k = 0; k < 4; k++) {
                int o = ob + 64 * i + k;
                h1row[o] = fmaxf(acc[i * 4 + k] * sga[o] + sba[o], 0.f);
            }
    }
    __syncthreads();
    {
        float acc[8];
#pragma unroll
        for (int i = 0; i < 8; i++) acc[i] = 0.f;
        const float* hrow = &sh1[r * 132];
        for (int c = 0; c < 128; c++) {
            float hv = hrow[c];
#pragma unroll
            for (int i = 0; i < 2; i++) {
                const float* wr = &sWb[c * 128 + ob + 64 * i];
#pragma unroll
                for (int k = 0; k < 4; k++)
                    acc[i * 4 + k] = fmaf(hv, wr[k], acc[i * 4 + k]);
            }
        }
        float* dst = h2out + (row0 + r) * 128;
#pragma unroll
        for (int i = 0; i < 2; i++)
#pragma unroll
            for (int k = 0; k < 4; k++) {
                int o = ob + 64 * i + k;
                dst[o] = fmaxf(acc[i * 4 + k] * sgb[o] + sbb[o], 0.f);
            }
    }
}

// ---------------------------------------------------------------------------
// K4b: out = LN(h2 @ Wc3 + bc3); LN via width-16 shuffle reduction
// ---------------------------------------------------------------------------
__global__ __launch_bounds__(256) void head2_kernel(
    const float* __restrict__ h2, const float* __restrict__ Wc3,
    const float* __restrict__ bc3, const float* __restrict__ lng,
    const float* __restrict__ lnb, float* __restrict__ out)
{
    __shared__ float sW[128 * 64];
    __shared__ float sh[16 * 132];
    __shared__ float sg[64], sb[64], sbc[64];
    const int t = threadIdx.x;
    const int row0 = blockIdx.x * 16;
    {
        const float4* w4 = (const float4*)Wc3;
        float4* dw = (float4*)sW;
#pragma unroll
        for (int k = 0; k < 8; k++) dw[t + k * 256] = w4[t + k * 256];
        if (t < 64) { sg[t] = lng[t]; sb[t] = lnb[t]; sbc[t] = bc3[t]; }
        const float4* h4 = (const float4*)(h2 + row0 * 128);
#pragma unroll
        for (int k = 0; k < 2; k++) {
            int e = t + k * 256;
            int r = e >> 5, c4 = (e & 31) * 4;
            *(float4*)&sh[r * 132 + c4] = h4[e];
        }
    }
    __syncthreads();
    const int r = t >> 4, o0 = (t & 15) * 4;
    float acc[4] = {0.f, 0.f, 0.f, 0.f};
    const float* hrow = &sh[r * 132];
    for (int c = 0; c < 128; c++) {
        float hv = hrow[c];
        const float* wr = &sW[c * 64 + o0];
#pragma unroll
        for (int k = 0; k < 4; k++) acc[k] = fmaf(hv, wr[k], acc[k]);
    }
#pragma unroll
    for (int k = 0; k < 4; k++) acc[k] += sbc[o0 + k];
    float s1 = acc[0] + acc[1] + acc[2] + acc[3];
    float s2 = acc[0] * acc[0] + acc[1] * acc[1] + acc[2] * acc[2] +
               acc[3] * acc[3];
#pragma unroll
    for (int d = 1; d < 16; d <<= 1) {
        s1 += __shfl_xor(s1, d, 16);
        s2 += __shfl_xor(s2, d, 16);
    }
    float m = s1 * (1.f / 64.f);
    float var = s2 * (1.f / 64.f) - m * m;
    float inv = 1.f / sqrtf(var + LN_EPS);
    float* dst = out + (row0 + r) * 64;
#pragma unroll
    for (int k = 0; k < 4; k++) {
        int o = o0 + k;
        dst[o] = (acc[k] - m) * inv * sg[o] + sb[o];
    }
}

// ---------------------------------------------------------------------------
extern "C" void kernel_launch(void* const* d_in, const int* in_sizes, int n_in,
                              void* d_out, int out_size, void* d_ws,
                              size_t ws_size, hipStream_t stream)
{
    const int* indices = (const int*)d_in[0];
    const float* feats = (const float*)d_in[1];
    const float* Wq = (const float*)d_in[2];
    const float* bq = (const float*)d_in[3];
    const float* Wk = (const float*)d_in[4];
    const float* bk = (const float*)d_in[5];
    const float* Wv = (const float*)d_in[6];
    const float* bv = (const float*)d_in[7];
    const float* Wp1 = (const float*)d_in[8];
    const float* pg = (const float*)d_in[9];
    const float* pb = (const float*)d_in[10];
    const float* Wp2 = (const float*)d_in[11];
    const float* bp2 = (const float*)d_in[12];
    const float* wg1 = (const float*)d_in[13];
    const float* wb1 = (const float*)d_in[14];
    const float* Ww1 = (const float*)d_in[15];
    const float* wg2 = (const float*)d_in[16];
    const float* wb2 = (const float*)d_in[17];
    const float* Ww2 = (const float*)d_in[18];
    const float* bw2 = (const float*)d_in[19];
    const float* Wc1 = (const float*)d_in[20];
    const float* cg1 = (const float*)d_in[21];
    const float* cb1 = (const float*)d_in[22];
    const float* Wc2 = (const float*)d_in[23];
    const float* cg2 = (const float*)d_in[24];
    const float* cb2 = (const float*)d_in[25];
    const float* Wc3 = (const float*)d_in[26];
    const float* bc3 = (const float*)d_in[27];
    const float* lng = (const float*)d_in[28];
    const float* lnb = (const float*)d_in[29];

    float* out = (float*)d_out;
    float* ws = (float*)d_ws;
    float* xq = ws;
    float* xk = xq + N * C;
    float* xv = xk + N * C;
    float* attn = xv + N * C;
    float* h2 = attn + N * C;             // N*128 floats
    int* knn = (int*)(h2 + N * 2 * C);    // N*16 ints

    qkv_kernel<<<256, 256, 0, stream>>>(feats, Wq, bq, Wk, bk, Wv, bv, xq, xk,
                                        xv);
    knn_kernel<<<512, 256, 0, stream>>>((const int4*)indices, knn);
    attn_kernel<<<2048, 512, 0, stream>>>((const int4*)indices, knn, xq, xk,
                                          xv, Wp1, pg, pb, Wp2, bp2, wg1, wb1,
                                          Ww1, wg2, wb2, Ww2, bw2, attn);
    head1_kernel<<<512, 256, 0, stream>>>(feats, attn, Wc1, cg1, cb1, Wc2,
                                          cg2, cb2, h2);
    head2_kernel<<<512, 256, 0, stream>>>(h2, Wc3, bc3, lng, lnb, out);
}

// Round 2
// 319.572 us; speedup vs baseline: 1.2653x; 1.2653x over previous
//
#include <hip/hip_runtime.h>

#define N 8192
#define C 64
#define S 16

static constexpr float BN_INV = 0.9999950000374997f; // 1/sqrt(1+1e-5)
static constexpr float LN_EPS = 1e-5f;

typedef _Float16 f16x8 __attribute__((ext_vector_type(8)));
typedef float f32x4 __attribute__((ext_vector_type(4)));

// ---------------------------------------------------------------------------
// K1: xq/xk/xv = feats @ W{q,k,v} + b  (8192x64 @ 64x64, f32)
// ---------------------------------------------------------------------------
__global__ __launch_bounds__(256) void qkv_kernel(
    const float* __restrict__ feats,
    const float* __restrict__ Wq, const float* __restrict__ bq,
    const float* __restrict__ Wk, const float* __restrict__ bk,
    const float* __restrict__ Wv, const float* __restrict__ bv,
    float* __restrict__ xq, float* __restrict__ xk, float* __restrict__ xv)
{
    __shared__ float sF[32 * 64];
    __shared__ float sW[3 * 64 * 64];
    const int t = threadIdx.x;
    const int row0 = blockIdx.x * 32;
    {
        const float4* src = (const float4*)(feats + row0 * 64);
        float4* dst = (float4*)sF;
        dst[t] = src[t];
        dst[t + 256] = src[t + 256];
        const float4* wq4 = (const float4*)Wq;
        const float4* wk4 = (const float4*)Wk;
        const float4* wv4 = (const float4*)Wv;
        float4* d0 = (float4*)sW;
        float4* d1 = (float4*)(sW + 4096);
        float4* d2 = (float4*)(sW + 8192);
#pragma unroll
        for (int k = 0; k < 4; k++) {
            d0[t + k * 256] = wq4[t + k * 256];
            d1[t + k * 256] = wk4[t + k * 256];
            d2[t + k * 256] = wv4[t + k * 256];
        }
    }
    __syncthreads();
    const int col = t & 63, rg = t >> 6;
    const float* biases[3] = {bq, bk, bv};
    float* outs[3] = {xq, xk, xv};
    for (int m = 0; m < 3; m++) {
        const float* w = sW + m * 4096;
        float bias = biases[m][col];
        float acc[8];
#pragma unroll
        for (int k = 0; k < 8; k++) acc[k] = bias;
        for (int c = 0; c < 64; c++) {
            float wv = w[c * 64 + col];
#pragma unroll
            for (int k = 0; k < 8; k++)
                acc[k] = fmaf(sF[(rg * 8 + k) * 64 + c], wv, acc[k]);
        }
        float* o = outs[m] + row0 * 64;
#pragma unroll
        for (int k = 0; k < 8; k++) o[(rg * 8 + k) * 64 + col] = acc[k];
    }
}

// ---------------------------------------------------------------------------
// K2: exact 16-NN by (d2, idx) ascending. key = (d2<<13)|idx (30 bits).
// 1024 blocks x 256 thr: 8 queries/block x 32 partitions. launch_bounds(256,4)
// caps VGPR at 128 so the 16-entry sorted list stays in registers (R1 spilled
// at the default occupancy target: VGPR_Count was 20 -> scratch).
// ---------------------------------------------------------------------------
__global__ __launch_bounds__(256, 4) void knn_kernel(
    const int4* __restrict__ idx4, int* __restrict__ knn_out)
{
    __shared__ int4 tile[512];
    const int t = threadIdx.x;
    const int p = t & 31, qi = t >> 5;
    const int q = blockIdx.x * 8 + qi;
    const int4 qc = idx4[q];
    const int qx = qc.y, qy = qc.z, qz = qc.w;
    unsigned a[16];
#pragma unroll
    for (int i = 0; i < 16; i++) a[i] = 0xFFFFFFFFu;

    for (int tb = 0; tb < 16; ++tb) {
        __syncthreads();
        tile[t] = idx4[tb * 512 + t];
        tile[t + 256] = idx4[tb * 512 + 256 + t];
        __syncthreads();
#pragma unroll 2
        for (int i = 0; i < 16; ++i) {
            int4 cd = tile[i * 32 + p];
            int j = tb * 512 + i * 32 + p;
            int dx = cd.y - qx, dy = cd.z - qy, dz = cd.w - qz;
            int d2 = dx * dx + dy * dy + dz * dz;
            unsigned key = ((unsigned)d2 << 13) | (unsigned)j;
            if (key < a[15]) {
                a[15] = key;
#pragma unroll
                for (int k = 15; k > 0; --k) {
                    unsigned lo = min(a[k - 1], a[k]);
                    unsigned hi = a[k - 1] ^ a[k] ^ lo;
                    a[k - 1] = lo;
                    a[k] = hi;
                }
            }
        }
    }
    // tournament merge of the 32 partition lists (width-32 shuffle groups)
    for (int r = 0; r < 16; ++r) {
        unsigned m = a[0];
        m = min(m, (unsigned)__shfl_xor((int)m, 1, 32));
        m = min(m, (unsigned)__shfl_xor((int)m, 2, 32));
        m = min(m, (unsigned)__shfl_xor((int)m, 4, 32));
        m = min(m, (unsigned)__shfl_xor((int)m, 8, 32));
        m = min(m, (unsigned)__shfl_xor((int)m, 16, 32));
        if (p == r) knn_out[q * 16 + r] = (int)(m & 8191u);
        if (a[0] == m) { // keys unique -> exactly one winner pops
#pragma unroll
            for (int k = 0; k < 15; ++k) a[k] = a[k + 1];
            a[15] = 0xFFFFFFFFu;
        }
    }
}

// ---------------------------------------------------------------------------
// K3: MFMA vector-attention. 512 blocks x 256 thr; one 64-lane wave per query
// (4 queries sequentially per wave). Barrier-free after weight staging.
// f16 16x16x32 MFMA: p_r MLP (1 zero-padded K), GEMM1 (2Kx8N), GEMM2 (4Kx4N).
// v stays in registers in C-layout; softmax/einsum via 4 regs + shfl_xor 16/32.
// LDS ~63KB -> 2 blocks/CU; launch_bounds(256,2) keeps arrays in VGPRs.
// ---------------------------------------------------------------------------
__global__ __launch_bounds__(256, 2) void attn_kernel(
    const int4* __restrict__ idx4, const int* __restrict__ knn,
    const float* __restrict__ xq, const float* __restrict__ xk,
    const float* __restrict__ xv,
    const float* __restrict__ Wp1, const float* __restrict__ pg,
    const float* __restrict__ pb, const float* __restrict__ Wp2,
    const float* __restrict__ bp2,
    const float* __restrict__ wg1, const float* __restrict__ wb1,
    const float* __restrict__ Ww1,
    const float* __restrict__ wg2, const float* __restrict__ wb2,
    const float* __restrict__ Ww2, const float* __restrict__ bw2,
    float* __restrict__ attn)
{
    // W1t[o][c]: o=0..127 rows, stride 72 halfs (2-way bank alias: free)
    __shared__ _Float16 sW1t[128 * 72];
    // W2t[m][n]: m=0..63 rows, stride 136 halfs
    __shared__ _Float16 sW2t[64 * 136];
    __shared__ _Float16 su[4 * 16 * 72];    // per-wave u scratch (A-layout)
    __shared__ _Float16 so1[4 * 16 * 136];  // per-wave o1 scratch (A-layout)
    __shared__ float sWp1[48], sPg[16], sPb[16];

    const int t = threadIdx.x;
    // stage transposed f16 weights
    for (int e = t; e < 8192; e += 256) {
        int c = e >> 7, o = e & 127;
        sW1t[o * 72 + c] = (_Float16)Ww1[e];
    }
    for (int e = t; e < 8192; e += 256) {
        int n = e >> 6, m = e & 63;
        sW2t[m * 136 + n] = (_Float16)Ww2[e];
    }
    if (t < 48) sWp1[t] = Wp1[t];
    if (t < 16) { sPg[t] = pg[t] * BN_INV; sPb[t] = pb[t]; }
    __syncthreads();

    const int lane = t & 63;
    const int wv = t >> 6;
    const int col = lane & 15, g = lane >> 4;

    // per-lane channel constants (c = f*16+col / o = f*16+col)
    float g1c[4], b1c[4], bp2c[4], bw2c[4], g2c[8], b2c[8];
#pragma unroll
    for (int f = 0; f < 4; f++) {
        int c = f * 16 + col;
        g1c[f] = wg1[c] * BN_INV; b1c[f] = wb1[c];
        bp2c[f] = bp2[c]; bw2c[f] = bw2[c];
    }
#pragma unroll
    for (int f = 0; f < 8; f++) {
        int o = f * 16 + col;
        g2c[f] = wg2[o] * BN_INV; b2c[f] = wb2[o];
    }
    // Wp2 B-fragments (K=32, zero-padded above h=16), resident
    f16x8 bP[4];
#pragma unroll
    for (int f = 0; f < 4; f++) {
#pragma unroll
        for (int j = 0; j < 8; j++) {
            int h = g * 8 + j;
            bP[f][j] = (g < 2) ? (_Float16)Wp2[h * 64 + f * 16 + col]
                               : (_Float16)0.f;
        }
    }
    _Float16* su_w = su + wv * (16 * 72);
    _Float16* so1_w = so1 + wv * (16 * 136);

    for (int it = 0; it < 4; ++it) {
        const int q = (blockIdx.x * 4 + wv) * 4 + it;
        // ---- p_r via MFMA: A = ph (row s = col), B = Wp2 ----
        const int jA = knn[q * 16 + col];
        const int4 pc = idx4[jA];
        const int4 qc = idx4[q];
        const float px = (float)(pc.y - qc.y);
        const float py = (float)(pc.z - qc.z);
        const float pz = (float)(pc.w - qc.w);
        f16x8 aph;
#pragma unroll
        for (int j = 0; j < 8; j++) {
            int h = g * 8 + j;
            float v = 0.f;
            if (g < 2) {
                v = px * sWp1[h] + py * sWp1[16 + h] + pz * sWp1[32 + h];
                v = fmaxf(v * sPg[h] + sPb[h], 0.f);
            }
            aph[j] = (_Float16)v;
        }
        f32x4 pr[4];
#pragma unroll
        for (int f = 0; f < 4; f++) {
            f32x4 cini;
#pragma unroll
            for (int r = 0; r < 4; r++) cini[r] = bp2c[f];
            pr[f] = __builtin_amdgcn_mfma_f32_16x16x32_f16(aph, bP[f], cini,
                                                           0, 0, 0);
        }
        // ---- u = relu(bn1(xk - xq + pr)) -> LDS(f16); v = xv + pr (regs) ----
        const int4 jC = *(const int4*)(knn + q * 16 + g * 4);
        const int jr[4] = {jC.x, jC.y, jC.z, jC.w};
        float xqv[4];
#pragma unroll
        for (int f = 0; f < 4; f++) xqv[f] = xq[q * 64 + f * 16 + col];
        f32x4 vvr[4];
#pragma unroll
        for (int r = 0; r < 4; r++) {
#pragma unroll
            for (int f = 0; f < 4; f++) {
                float xkv = xk[jr[r] * 64 + f * 16 + col];
                float xvv = xv[jr[r] * 64 + f * 16 + col];
                float w0 = xkv - xqv[f] + pr[f][r];
                float uu = fmaxf(w0 * g1c[f] + b1c[f], 0.f);
                su_w[(g * 4 + r) * 72 + f * 16 + col] = (_Float16)uu;
                vvr[f][r] = xvv + pr[f][r];
            }
        }
        // ---- GEMM1: o1 = relu(bn2(u @ W1)) ----
        f16x8 au[2];
#pragma unroll
        for (int kc = 0; kc < 2; kc++)
            au[kc] = *(const f16x8*)&su_w[col * 72 + kc * 32 + g * 8];
        f32x4 acc1[8];
#pragma unroll
        for (int f = 0; f < 8; f++)
#pragma unroll
            for (int r = 0; r < 4; r++) acc1[f][r] = 0.f;
#pragma unroll
        for (int kc = 0; kc < 2; kc++) {
#pragma unroll
            for (int f = 0; f < 8; f++) {
                f16x8 bw = *(const f16x8*)
                    &sW1t[(f * 16 + col) * 72 + kc * 32 + g * 8];
                acc1[f] = __builtin_amdgcn_mfma_f32_16x16x32_f16(au[kc], bw,
                                                                 acc1[f],
                                                                 0, 0, 0);
            }
        }
#pragma unroll
        for (int f = 0; f < 8; f++)
#pragma unroll
            for (int r = 0; r < 4; r++) {
                float o1 = fmaxf(acc1[f][r] * g2c[f] + b2c[f], 0.f);
                so1_w[(g * 4 + r) * 136 + f * 16 + col] = (_Float16)o1;
            }
        // ---- GEMM2: logits = o1 @ W2 + bw2 ----
        f16x8 ao[4];
#pragma unroll
        for (int kc = 0; kc < 4; kc++)
            ao[kc] = *(const f16x8*)&so1_w[col * 136 + kc * 32 + g * 8];
        f32x4 accL[4];
#pragma unroll
        for (int f = 0; f < 4; f++)
#pragma unroll
            for (int r = 0; r < 4; r++) accL[f][r] = bw2c[f];
#pragma unroll
        for (int kc = 0; kc < 4; kc++) {
#pragma unroll
            for (int f = 0; f < 4; f++) {
                f16x8 bw = *(const f16x8*)
                    &sW2t[(f * 16 + col) * 136 + kc * 32 + g * 8];
                accL[f] = __builtin_amdgcn_mfma_f32_16x16x32_f16(ao[kc], bw,
                                                                 accL[f],
                                                                 0, 0, 0);
            }
        }
        // ---- softmax over s (4 regs + groups via shfl 16/32) + einsum ----
        float outv[4];
#pragma unroll
        for (int f = 0; f < 4; f++) {
            float mx = fmaxf(fmaxf(accL[f][0], accL[f][1]),
                             fmaxf(accL[f][2], accL[f][3]));
            mx = fmaxf(mx, __shfl_xor(mx, 16, 64));
            mx = fmaxf(mx, __shfl_xor(mx, 32, 64));
            float sum = 0.f, part = 0.f;
#pragma unroll
            for (int r = 0; r < 4; r++) {
                float e = __expf(accL[f][r] - mx);
                sum += e;
                part = fmaf(e, vvr[f][r], part);
            }
            sum += __shfl_xor(sum, 16, 64);
            sum += __shfl_xor(sum, 32, 64);
            part += __shfl_xor(part, 16, 64);
            part += __shfl_xor(part, 32, 64);
            outv[f] = part / sum;
        }
        float val = (g == 0) ? outv[0]
                  : (g == 1) ? outv[1]
                  : (g == 2) ? outv[2] : outv[3];
        attn[q * 64 + lane] = val; // lane == g*16+col -> coalesced 64 floats
    }
}

// ---------------------------------------------------------------------------
// K4a: h2 = relu(bn(relu(bn([feats,attn] @ Wc1)) @ Wc2))
// ---------------------------------------------------------------------------
__global__ __launch_bounds__(256) void head1_kernel(
    const float* __restrict__ feats, const float* __restrict__ attn,
    const float* __restrict__ Wc1, const float* __restrict__ cg1,
    const float* __restrict__ cb1, const float* __restrict__ Wc2,
    const float* __restrict__ cg2, const float* __restrict__ cb2,
    float* __restrict__ h2out)
{
    __shared__ float sWa[128 * 128];
    __shared__ float sWb[128 * 128];
    __shared__ float sh[16 * 132];
    __shared__ float sh1[16 * 132];
    __shared__ float sga[128], sba[128], sgb[128], sbb[128];
    const int t = threadIdx.x;
    const int row0 = blockIdx.x * 16;
    {
        const float4* a4 = (const float4*)Wc1;
        const float4* b4 = (const float4*)Wc2;
        float4* da = (float4*)sWa;
        float4* db = (float4*)sWb;
#pragma unroll
        for (int k = 0; k < 16; k++) {
            da[t + k * 256] = a4[t + k * 256];
            db[t + k * 256] = b4[t + k * 256];
        }
        if (t < 128) {
            sga[t] = cg1[t] * BN_INV; sba[t] = cb1[t];
            sgb[t] = cg2[t] * BN_INV; sbb[t] = cb2[t];
        }
    }
#pragma unroll
    for (int k = 0; k < 8; k++) {
        int e = t + k * 256;
        int r = e >> 7, c = e & 127;
        float xval = (c < 64) ? feats[(row0 + r) * 64 + c]
                              : attn[(row0 + r) * 64 + (c - 64)];
        sh[r * 132 + c] = xval;
    }
    __syncthreads();
    const int r = t >> 4, ob = (t & 15) * 4;
    {
        float acc[8];
#pragma unroll
        for (int i = 0; i < 8; i++) acc[i] = 0.f;
        const float* hrow = &sh[r * 132];
        for (int c = 0; c < 128; c++) {
            float hv = hrow[c];
#pragma unroll
            for (int i = 0; i < 2; i++) {
                const float* wr = &sWa[c * 128 + ob + 64 * i];
#pragma unroll
                for (int k = 0; k < 4; k++)
                    acc[i * 4 + k] = fmaf(hv, wr[k], acc[i * 4 + k]);
            }
        }
        float* h1row = &sh1[r * 132];
#pragma unroll
        for (int i = 0; i < 2; i++)
#pragma unroll
            for (int k = 0; k < 4; k++) {
                int o = ob + 64 * i + k;
                h1row[o] = fmaxf(acc[i * 4 + k] * sga[o] + sba[o], 0.f);
            }
    }
    __syncthreads();
    {
        float acc[8];
#pragma unroll
        for (int i = 0; i < 8; i++) acc[i] = 0.f;
        const float* hrow = &sh1[r * 132];
        for (int c = 0; c < 128; c++) {
            float hv = hrow[c];
#pragma unroll
            for (int i = 0; i < 2; i++) {
                const float* wr = &sWb[c * 128 + ob + 64 * i];
#pragma unroll
                for (int k = 0; k < 4; k++)
                    acc[i * 4 + k] = fmaf(hv, wr[k], acc[i * 4 + k]);
            }
        }
        float* dst = h2out + (row0 + r) * 128;
#pragma unroll
        for (int i = 0; i < 2; i++)
#pragma unroll
            for (int k = 0; k < 4; k++) {
                int o = ob + 64 * i + k;
                dst[o] = fmaxf(acc[i * 4 + k] * sgb[o] + sbb[o], 0.f);
            }
    }
}

// ---------------------------------------------------------------------------
// K4b: out = LN(h2 @ Wc3 + bc3)
// ---------------------------------------------------------------------------
__global__ __launch_bounds__(256) void head2_kernel(
    const float* __restrict__ h2, const float* __restrict__ Wc3,
    const float* __restrict__ bc3, const float* __restrict__ lng,
    const float* __restrict__ lnb, float* __restrict__ out)
{
    __shared__ float sW[128 * 64];
    __shared__ float sh[16 * 132];
    __shared__ float sg[64], sb[64], sbc[64];
    const int t = threadIdx.x;
    const int row0 = blockIdx.x * 16;
    {
        const float4* w4 = (const float4*)Wc3;
        float4* dw = (float4*)sW;
#pragma unroll
        for (int k = 0; k < 8; k++) dw[t + k * 256] = w4[t + k * 256];
        if (t < 64) { sg[t] = lng[t]; sb[t] = lnb[t]; sbc[t] = bc3[t]; }
        const float4* h4 = (const float4*)(h2 + row0 * 128);
#pragma unroll
        for (int k = 0; k < 2; k++) {
            int e = t + k * 256;
            int r = e >> 5, c4 = (e & 31) * 4;
            *(float4*)&sh[r * 132 + c4] = h4[e];
        }
    }
    __syncthreads();
    const int r = t >> 4, o0 = (t & 15) * 4;
    float acc[4] = {0.f, 0.f, 0.f, 0.f};
    const float* hrow = &sh[r * 132];
    for (int c = 0; c < 128; c++) {
        float hv = hrow[c];
        const float* wr = &sW[c * 64 + o0];
#pragma unroll
        for (int k = 0; k < 4; k++) acc[k] = fmaf(hv, wr[k], acc[k]);
    }
#pragma unroll
    for (int k = 0; k < 4; k++) acc[k] += sbc[o0 + k];
    float s1 = acc[0] + acc[1] + acc[2] + acc[3];
    float s2 = acc[0] * acc[0] + acc[1] * acc[1] + acc[2] * acc[2] +
               acc[3] * acc[3];
#pragma unroll
    for (int d = 1; d < 16; d <<= 1) {
        s1 += __shfl_xor(s1, d, 16);
        s2 += __shfl_xor(s2, d, 16);
    }
    float m = s1 * (1.f / 64.f);
    float var = s2 * (1.f / 64.f) - m * m;
    float inv = 1.f / sqrtf(var + LN_EPS);
    float* dst = out + (row0 + r) * 64;
#pragma unroll
    for (int k = 0; k < 4; k++) {
        int o = o0 + k;
        dst[o] = (acc[k] - m) * inv * sg[o] + sb[o];
    }
}

// ---------------------------------------------------------------------------
extern "C" void kernel_launch(void* const* d_in, const int* in_sizes, int n_in,
                              void* d_out, int out_size, void* d_ws,
                              size_t ws_size, hipStream_t stream)
{
    const int* indices = (const int*)d_in[0];
    const float* feats = (const float*)d_in[1];
    const float* Wq = (const float*)d_in[2];
    const float* bq = (const float*)d_in[3];
    const float* Wk = (const float*)d_in[4];
    const float* bk = (const float*)d_in[5];
    const float* Wv = (const float*)d_in[6];
    const float* bv = (const float*)d_in[7];
    const float* Wp1 = (const float*)d_in[8];
    const float* pg = (const float*)d_in[9];
    const float* pb = (const float*)d_in[10];
    const float* Wp2 = (const float*)d_in[11];
    const float* bp2 = (const float*)d_in[12];
    const float* wg1 = (const float*)d_in[13];
    const float* wb1 = (const float*)d_in[14];
    const float* Ww1 = (const float*)d_in[15];
    const float* wg2 = (const float*)d_in[16];
    const float* wb2 = (const float*)d_in[17];
    const float* Ww2 = (const float*)d_in[18];
    const float* bw2 = (const float*)d_in[19];
    const float* Wc1 = (const float*)d_in[20];
    const float* cg1 = (const float*)d_in[21];
    const float* cb1 = (const float*)d_in[22];
    const float* Wc2 = (const float*)d_in[23];
    const float* cg2 = (const float*)d_in[24];
    const float* cb2 = (const float*)d_in[25];
    const float* Wc3 = (const float*)d_in[26];
    const float* bc3 = (const float*)d_in[27];
    const float* lng = (const float*)d_in[28];
    const float* lnb = (const float*)d_in[29];

    float* out = (float*)d_out;
    float* ws = (float*)d_ws;
    float* xq = ws;
    float* xk = xq + N * C;
    float* xv = xk + N * C;
    float* attn = xv + N * C;
    float* h2 = attn + N * C;             // N*128 floats
    int* knn = (int*)(h2 + N * 2 * C);    // N*16 ints

    qkv_kernel<<<256, 256, 0, stream>>>(feats, Wq, bq, Wk, bk, Wv, bv, xq, xk,
                                        xv);
    knn_kernel<<<1024, 256, 0, stream>>>((const int4*)indices, knn);
    attn_kernel<<<512, 256, 0, stream>>>((const int4*)indices, knn, xq, xk,
                                         xv, Wp1, pg, pb, Wp2, bp2, wg1, wb1,
                                         Ww1, wg2, wb2, Ww2, bw2, attn);
    head1_kernel<<<512, 256, 0, stream>>>(feats, attn, Wc1, cg1, cb1, Wc2,
                                          cg2, cb2, h2);
    head2_kernel<<<512, 256, 0, stream>>>(h2, Wc3, bc3, lng, lnb, out);
}

// Round 3
// 274.114 us; speedup vs baseline: 1.4751x; 1.1658x over previous
//
#include <hip/hip_runtime.h>

#define N 8192
#define C 64
#define S 16

static constexpr float BN_INV = 0.9999950000374997f; // 1/sqrt(1+1e-5)
static constexpr float LN_EPS = 1e-5f;

typedef _Float16 f16x8 __attribute__((ext_vector_type(8)));
typedef float f32x4 __attribute__((ext_vector_type(4)));

// ---------------------------------------------------------------------------
// K1: xq/xk/xv = feats @ W{q,k,v} + b  (8192x64 @ 64x64, f32)
// ---------------------------------------------------------------------------
__global__ __launch_bounds__(256) void qkv_kernel(
    const float* __restrict__ feats,
    const float* __restrict__ Wq, const float* __restrict__ bq,
    const float* __restrict__ Wk, const float* __restrict__ bk,
    const float* __restrict__ Wv, const float* __restrict__ bv,
    float* __restrict__ xq, float* __restrict__ xk, float* __restrict__ xv)
{
    __shared__ float sF[32 * 64];
    __shared__ float sW[3 * 64 * 64];
    const int t = threadIdx.x;
    const int row0 = blockIdx.x * 32;
    {
        const float4* src = (const float4*)(feats + row0 * 64);
        float4* dst = (float4*)sF;
        dst[t] = src[t];
        dst[t + 256] = src[t + 256];
        const float4* wq4 = (const float4*)Wq;
        const float4* wk4 = (const float4*)Wk;
        const float4* wv4 = (const float4*)Wv;
        float4* d0 = (float4*)sW;
        float4* d1 = (float4*)(sW + 4096);
        float4* d2 = (float4*)(sW + 8192);
#pragma unroll
        for (int k = 0; k < 4; k++) {
            d0[t + k * 256] = wq4[t + k * 256];
            d1[t + k * 256] = wk4[t + k * 256];
            d2[t + k * 256] = wv4[t + k * 256];
        }
    }
    __syncthreads();
    const int col = t & 63, rg = t >> 6;
    const float* biases[3] = {bq, bk, bv};
    float* outs[3] = {xq, xk, xv};
    for (int m = 0; m < 3; m++) {
        const float* w = sW + m * 4096;
        float bias = biases[m][col];
        float acc[8];
#pragma unroll
        for (int k = 0; k < 8; k++) acc[k] = bias;
        for (int c = 0; c < 64; c++) {
            float wv = w[c * 64 + col];
#pragma unroll
            for (int k = 0; k < 8; k++)
                acc[k] = fmaf(sF[(rg * 8 + k) * 64 + c], wv, acc[k]);
        }
        float* o = outs[m] + row0 * 64;
#pragma unroll
        for (int k = 0; k < 8; k++) o[(rg * 8 + k) * 64 + col] = acc[k];
    }
}

// ---------------------------------------------------------------------------
// K2: exact 16-NN by (d2, idx) ascending. key = (d2<<13)|idx (30 bits).
// One query per 64-lane wave; lane = partition (stride 64), 128 cands/lane.
// Top-16 held in 16 NAMED registers (no alloca -> no scratch; R1/R2 spilled:
// VGPR_Count=20). Branch-free insert: a15=min(a15,key) + 15 sort2. SoA int
// tile in LDS -> stride-1 b32 reads (2 lanes/bank = free). Width-64 shuffle
// tournament merge with cndmask pops.
// ---------------------------------------------------------------------------
__device__ __forceinline__ void sort2(unsigned& x, unsigned& y)
{
    unsigned lo = min(x, y);
    unsigned hi = max(x, y);
    x = lo;
    y = hi;
}

__global__ __launch_bounds__(256) void knn_kernel(
    const int4* __restrict__ idx4, int* __restrict__ knn_out)
{
    __shared__ int tx[512], ty[512], tz[512];
    const int t = threadIdx.x;
    const int lane = t & 63;
    const int wv = t >> 6;
    const int q = blockIdx.x * 4 + wv;
    const int4 qc = idx4[q];
    const int qx = qc.y, qy = qc.z, qz = qc.w;
    unsigned a0 = 0xFFFFFFFFu, a1 = 0xFFFFFFFFu, a2 = 0xFFFFFFFFu,
             a3 = 0xFFFFFFFFu, a4 = 0xFFFFFFFFu, a5 = 0xFFFFFFFFu,
             a6 = 0xFFFFFFFFu, a7 = 0xFFFFFFFFu, a8 = 0xFFFFFFFFu,
             a9 = 0xFFFFFFFFu, a10 = 0xFFFFFFFFu, a11 = 0xFFFFFFFFu,
             a12 = 0xFFFFFFFFu, a13 = 0xFFFFFFFFu, a14 = 0xFFFFFFFFu,
             a15 = 0xFFFFFFFFu;

    for (int tb = 0; tb < 16; ++tb) {
        __syncthreads();
        {
            int4 c0 = idx4[tb * 512 + t];
            int4 c1 = idx4[tb * 512 + 256 + t];
            tx[t] = c0.y; ty[t] = c0.z; tz[t] = c0.w;
            tx[t + 256] = c1.y; ty[t + 256] = c1.z; tz[t + 256] = c1.w;
        }
        __syncthreads();
#pragma unroll
        for (int i = 0; i < 8; ++i) {
            int e = i * 64 + lane;
            int dx = tx[e] - qx, dy = ty[e] - qy, dz = tz[e] - qz;
            unsigned d2 = (unsigned)(dx * dx + dy * dy + dz * dz);
            unsigned key = (d2 << 13) | (unsigned)(tb * 512 + e);
            a15 = min(a15, key);
            sort2(a14, a15); sort2(a13, a14); sort2(a12, a13);
            sort2(a11, a12); sort2(a10, a11); sort2(a9, a10);
            sort2(a8, a9);   sort2(a7, a8);   sort2(a6, a7);
            sort2(a5, a6);   sort2(a4, a5);   sort2(a3, a4);
            sort2(a2, a3);   sort2(a1, a2);   sort2(a0, a1);
        }
    }
    for (int r = 0; r < 16; ++r) {
        unsigned m = a0;
        m = min(m, (unsigned)__shfl_xor((int)m, 1, 64));
        m = min(m, (unsigned)__shfl_xor((int)m, 2, 64));
        m = min(m, (unsigned)__shfl_xor((int)m, 4, 64));
        m = min(m, (unsigned)__shfl_xor((int)m, 8, 64));
        m = min(m, (unsigned)__shfl_xor((int)m, 16, 64));
        m = min(m, (unsigned)__shfl_xor((int)m, 32, 64));
        if (lane == r) knn_out[q * 16 + r] = (int)(m & 8191u);
        bool win = (a0 == m); // keys unique -> exactly one winner pops
        a0 = win ? a1 : a0;    a1 = win ? a2 : a1;
        a2 = win ? a3 : a2;    a3 = win ? a4 : a3;
        a4 = win ? a5 : a4;    a5 = win ? a6 : a5;
        a6 = win ? a7 : a6;    a7 = win ? a8 : a7;
        a8 = win ? a9 : a8;    a9 = win ? a10 : a9;
        a10 = win ? a11 : a10; a11 = win ? a12 : a11;
        a12 = win ? a13 : a12; a13 = win ? a14 : a13;
        a14 = win ? a15 : a14; a15 = win ? 0xFFFFFFFFu : a15;
    }
}

// ---------------------------------------------------------------------------
// K3: MFMA vector-attention. 512 blocks x 256 thr; one 64-lane wave per query
// (4 queries sequentially per wave). Barrier-free after weight staging.
// ---------------------------------------------------------------------------
__global__ __launch_bounds__(256, 2) void attn_kernel(
    const int4* __restrict__ idx4, const int* __restrict__ knn,
    const float* __restrict__ xq, const float* __restrict__ xk,
    const float* __restrict__ xv,
    const float* __restrict__ Wp1, const float* __restrict__ pg,
    const float* __restrict__ pb, const float* __restrict__ Wp2,
    const float* __restrict__ bp2,
    const float* __restrict__ wg1, const float* __restrict__ wb1,
    const float* __restrict__ Ww1,
    const float* __restrict__ wg2, const float* __restrict__ wb2,
    const float* __restrict__ Ww2, const float* __restrict__ bw2,
    float* __restrict__ attn)
{
    __shared__ _Float16 sW1t[128 * 72];
    __shared__ _Float16 sW2t[64 * 136];
    __shared__ _Float16 su[4 * 16 * 72];
    __shared__ _Float16 so1[4 * 16 * 136];
    __shared__ float sWp1[48], sPg[16], sPb[16];

    const int t = threadIdx.x;
    for (int e = t; e < 8192; e += 256) {
        int c = e >> 7, o = e & 127;
        sW1t[o * 72 + c] = (_Float16)Ww1[e];
    }
    for (int e = t; e < 8192; e += 256) {
        int n = e >> 6, m = e & 63;
        sW2t[m * 136 + n] = (_Float16)Ww2[e];
    }
    if (t < 48) sWp1[t] = Wp1[t];
    if (t < 16) { sPg[t] = pg[t] * BN_INV; sPb[t] = pb[t]; }
    __syncthreads();

    const int lane = t & 63;
    const int wv = t >> 6;
    const int col = lane & 15, g = lane >> 4;

    float g1c[4], b1c[4], bp2c[4], bw2c[4], g2c[8], b2c[8];
#pragma unroll
    for (int f = 0; f < 4; f++) {
        int c = f * 16 + col;
        g1c[f] = wg1[c] * BN_INV; b1c[f] = wb1[c];
        bp2c[f] = bp2[c]; bw2c[f] = bw2[c];
    }
#pragma unroll
    for (int f = 0; f < 8; f++) {
        int o = f * 16 + col;
        g2c[f] = wg2[o] * BN_INV; b2c[f] = wb2[o];
    }
    f16x8 bP[4];
#pragma unroll
    for (int f = 0; f < 4; f++) {
#pragma unroll
        for (int j = 0; j < 8; j++) {
            int h = g * 8 + j;
            bP[f][j] = (g < 2) ? (_Float16)Wp2[h * 64 + f * 16 + col]
                               : (_Float16)0.f;
        }
    }
    _Float16* su_w = su + wv * (16 * 72);
    _Float16* so1_w = so1 + wv * (16 * 136);

    for (int it = 0; it < 4; ++it) {
        const int q = (blockIdx.x * 4 + wv) * 4 + it;
        const int jA = knn[q * 16 + col];
        const int4 pc = idx4[jA];
        const int4 qc = idx4[q];
        const float px = (float)(pc.y - qc.y);
        const float py = (float)(pc.z - qc.z);
        const float pz = (float)(pc.w - qc.w);
        f16x8 aph;
#pragma unroll
        for (int j = 0; j < 8; j++) {
            int h = g * 8 + j;
            float v = 0.f;
            if (g < 2) {
                v = px * sWp1[h] + py * sWp1[16 + h] + pz * sWp1[32 + h];
                v = fmaxf(v * sPg[h] + sPb[h], 0.f);
            }
            aph[j] = (_Float16)v;
        }
        f32x4 pr[4];
#pragma unroll
        for (int f = 0; f < 4; f++) {
            f32x4 cini;
#pragma unroll
            for (int r = 0; r < 4; r++) cini[r] = bp2c[f];
            pr[f] = __builtin_amdgcn_mfma_f32_16x16x32_f16(aph, bP[f], cini,
                                                           0, 0, 0);
        }
        const int4 jC = *(const int4*)(knn + q * 16 + g * 4);
        const int jr[4] = {jC.x, jC.y, jC.z, jC.w};
        float xqv[4];
#pragma unroll
        for (int f = 0; f < 4; f++) xqv[f] = xq[q * 64 + f * 16 + col];
        f32x4 vvr[4];
#pragma unroll
        for (int r = 0; r < 4; r++) {
#pragma unroll
            for (int f = 0; f < 4; f++) {
                float xkv = xk[jr[r] * 64 + f * 16 + col];
                float xvv = xv[jr[r] * 64 + f * 16 + col];
                float w0 = xkv - xqv[f] + pr[f][r];
                float uu = fmaxf(w0 * g1c[f] + b1c[f], 0.f);
                su_w[(g * 4 + r) * 72 + f * 16 + col] = (_Float16)uu;
                vvr[f][r] = xvv + pr[f][r];
            }
        }
        f16x8 au[2];
#pragma unroll
        for (int kc = 0; kc < 2; kc++)
            au[kc] = *(const f16x8*)&su_w[col * 72 + kc * 32 + g * 8];
        f32x4 acc1[8];
#pragma unroll
        for (int f = 0; f < 8; f++)
#pragma unroll
            for (int r = 0; r < 4; r++) acc1[f][r] = 0.f;
#pragma unroll
        for (int kc = 0; kc < 2; kc++) {
#pragma unroll
            for (int f = 0; f < 8; f++) {
                f16x8 bw = *(const f16x8*)
                    &sW1t[(f * 16 + col) * 72 + kc * 32 + g * 8];
                acc1[f] = __builtin_amdgcn_mfma_f32_16x16x32_f16(au[kc], bw,
                                                                 acc1[f],
                                                                 0, 0, 0);
            }
        }
#pragma unroll
        for (int f = 0; f < 8; f++)
#pragma unroll
            for (int r = 0; r < 4; r++) {
                float o1 = fmaxf(acc1[f][r] * g2c[f] + b2c[f], 0.f);
                so1_w[(g * 4 + r) * 136 + f * 16 + col] = (_Float16)o1;
            }
        f16x8 ao[4];
#pragma unroll
        for (int kc = 0; kc < 4; kc++)
            ao[kc] = *(const f16x8*)&so1_w[col * 136 + kc * 32 + g * 8];
        f32x4 accL[4];
#pragma unroll
        for (int f = 0; f < 4; f++)
#pragma unroll
            for (int r = 0; r < 4; r++) accL[f][r] = bw2c[f];
#pragma unroll
        for (int kc = 0; kc < 4; kc++) {
#pragma unroll
            for (int f = 0; f < 4; f++) {
                f16x8 bw = *(const f16x8*)
                    &sW2t[(f * 16 + col) * 136 + kc * 32 + g * 8];
                accL[f] = __builtin_amdgcn_mfma_f32_16x16x32_f16(ao[kc], bw,
                                                                 accL[f],
                                                                 0, 0, 0);
            }
        }
        float outv[4];
#pragma unroll
        for (int f = 0; f < 4; f++) {
            float mx = fmaxf(fmaxf(accL[f][0], accL[f][1]),
                             fmaxf(accL[f][2], accL[f][3]));
            mx = fmaxf(mx, __shfl_xor(mx, 16, 64));
            mx = fmaxf(mx, __shfl_xor(mx, 32, 64));
            float sum = 0.f, part = 0.f;
#pragma unroll
            for (int r = 0; r < 4; r++) {
                float e = __expf(accL[f][r] - mx);
                sum += e;
                part = fmaf(e, vvr[f][r], part);
            }
            sum += __shfl_xor(sum, 16, 64);
            sum += __shfl_xor(sum, 32, 64);
            part += __shfl_xor(part, 16, 64);
            part += __shfl_xor(part, 32, 64);
            outv[f] = part / sum;
        }
        float val = (g == 0) ? outv[0]
                  : (g == 1) ? outv[1]
                  : (g == 2) ? outv[2] : outv[3];
        attn[q * 64 + lane] = val;
    }
}

// ---------------------------------------------------------------------------
// K4a: h2 = relu(bn(relu(bn([feats,attn] @ Wc1)) @ Wc2))
// ---------------------------------------------------------------------------
__global__ __launch_bounds__(256) void head1_kernel(
    const float* __restrict__ feats, const float* __restrict__ attn,
    const float* __restrict__ Wc1, const float* __restrict__ cg1,
    const float* __restrict__ cb1, const float* __restrict__ Wc2,
    const float* __restrict__ cg2, const float* __restrict__ cb2,
    float* __restrict__ h2out)
{
    __shared__ float sWa[128 * 128];
    __shared__ float sWb[128 * 128];
    __shared__ float sh[16 * 132];
    __shared__ float sh1[16 * 132];
    __shared__ float sga[128], sba[128], sgb[128], sbb[128];
    const int t = threadIdx.x;
    const int row0 = blockIdx.x * 16;
    {
        const float4* a4 = (const float4*)Wc1;
        const float4* b4 = (const float4*)Wc2;
        float4* da = (float4*)sWa;
        float4* db = (float4*)sWb;
#pragma unroll
        for (int k = 0; k < 16; k++) {
            da[t + k * 256] = a4[t + k * 256];
            db[t + k * 256] = b4[t + k * 256];
        }
        if (t < 128) {
            sga[t] = cg1[t] * BN_INV; sba[t] = cb1[t];
            sgb[t] = cg2[t] * BN_INV; sbb[t] = cb2[t];
        }
    }
#pragma unroll
    for (int k = 0; k < 8; k++) {
        int e = t + k * 256;
        int r = e >> 7, c = e & 127;
        float xval = (c < 64) ? feats[(row0 + r) * 64 + c]
                              : attn[(row0 + r) * 64 + (c - 64)];
        sh[r * 132 + c] = xval;
    }
    __syncthreads();
    const int r = t >> 4, ob = (t & 15) * 4;
    {
        float acc[8];
#pragma unroll
        for (int i = 0; i < 8; i++) acc[i] = 0.f;
        const float* hrow = &sh[r * 132];
        for (int c = 0; c < 128; c++) {
            float hv = hrow[c];
#pragma unroll
            for (int i = 0; i < 2; i++) {
                const float* wr = &sWa[c * 128 + ob + 64 * i];
#pragma unroll
                for (int k = 0; k < 4; k++)
                    acc[i * 4 + k] = fmaf(hv, wr[k], acc[i * 4 + k]);
            }
        }
        float* h1row = &sh1[r * 132];
#pragma unroll
        for (int i = 0; i < 2; i++)
#pragma unroll
            for (int k = 0; k < 4; k++) {
                int o = ob + 64 * i + k;
                h1row[o] = fmaxf(acc[i * 4 + k] * sga[o] + sba[o], 0.f);
            }
    }
    __syncthreads();
    {
        float acc[8];
#pragma unroll
        for (int i = 0; i < 8; i++) acc[i] = 0.f;
        const float* hrow = &sh1[r * 132];
        for (int c = 0; c < 128; c++) {
            float hv = hrow[c];
#pragma unroll
            for (int i = 0; i < 2; i++) {
                const float* wr = &sWb[c * 128 + ob + 64 * i];
#pragma unroll
                for (int k = 0; k < 4; k++)
                    acc[i * 4 + k] = fmaf(hv, wr[k], acc[i * 4 + k]);
            }
        }
        float* dst = h2out + (row0 + r) * 128;
#pragma unroll
        for (int i = 0; i < 2; i++)
#pragma unroll
            for (int k = 0; k < 4; k++) {
                int o = ob + 64 * i + k;
                dst[o] = fmaxf(acc[i * 4 + k] * sgb[o] + sbb[o], 0.f);
            }
    }
}

// ---------------------------------------------------------------------------
// K4b: out = LN(h2 @ Wc3 + bc3)
// ---------------------------------------------------------------------------
__global__ __launch_bounds__(256) void head2_kernel(
    const float* __restrict__ h2, const float* __restrict__ Wc3,
    const float* __restrict__ bc3, const float* __restrict__ lng,
    const float* __restrict__ lnb, float* __restrict__ out)
{
    __shared__ float sW[128 * 64];
    __shared__ float sh[16 * 132];
    __shared__ float sg[64], sb[64], sbc[64];
    const int t = threadIdx.x;
    const int row0 = blockIdx.x * 16;
    {
        const float4* w4 = (const float4*)Wc3;
        float4* dw = (float4*)sW;
#pragma unroll
        for (int k = 0; k < 8; k++) dw[t + k * 256] = w4[t + k * 256];
        if (t < 64) { sg[t] = lng[t]; sb[t] = lnb[t]; sbc[t] = bc3[t]; }
        const float4* h4 = (const float4*)(h2 + row0 * 128);
#pragma unroll
        for (int k = 0; k < 2; k++) {
            int e = t + k * 256;
            int r = e >> 5, c4 = (e & 31) * 4;
            *(float4*)&sh[r * 132 + c4] = h4[e];
        }
    }
    __syncthreads();
    const int r = t >> 4, o0 = (t & 15) * 4;
    float acc[4] = {0.f, 0.f, 0.f, 0.f};
    const float* hrow = &sh[r * 132];
    for (int c = 0; c < 128; c++) {
        float hv = hrow[c];
        const float* wr = &sW[c * 64 + o0];
#pragma unroll
        for (int k = 0; k < 4; k++) acc[k] = fmaf(hv, wr[k], acc[k]);
    }
#pragma unroll
    for (int k = 0; k < 4; k++) acc[k] += sbc[o0 + k];
    float s1 = acc[0] + acc[1] + acc[2] + acc[3];
    float s2 = acc[0] * acc[0] + acc[1] * acc[1] + acc[2] * acc[2] +
               acc[3] * acc[3];
#pragma unroll
    for (int d = 1; d < 16; d <<= 1) {
        s1 += __shfl_xor(s1, d, 16);
        s2 += __shfl_xor(s2, d, 16);
    }
    float m = s1 * (1.f / 64.f);
    float var = s2 * (1.f / 64.f) - m * m;
    float inv = 1.f / sqrtf(var + LN_EPS);
    float* dst = out + (row0 + r) * 64;
#pragma unroll
    for (int k = 0; k < 4; k++) {
        int o = o0 + k;
        dst[o] = (acc[k] - m) * inv * sg[o] + sb[o];
    }
}

// ---------------------------------------------------------------------------
extern "C" void kernel_launch(void* const* d_in, const int* in_sizes, int n_in,
                              void* d_out, int out_size, void* d_ws,
                              size_t ws_size, hipStream_t stream)
{
    const int* indices = (const int*)d_in[0];
    const float* feats = (const float*)d_in[1];
    const float* Wq = (const float*)d_in[2];
    const float* bq = (const float*)d_in[3];
    const float* Wk = (const float*)d_in[4];
    const float* bk = (const float*)d_in[5];
    const float* Wv = (const float*)d_in[6];
    const float* bv = (const float*)d_in[7];
    const float* Wp1 = (const float*)d_in[8];
    const float* pg = (const float*)d_in[9];
    const float* pb = (const float*)d_in[10];
    const float* Wp2 = (const float*)d_in[11];
    const float* bp2 = (const float*)d_in[12];
    const float* wg1 = (const float*)d_in[13];
    const float* wb1 = (const float*)d_in[14];
    const float* Ww1 = (const float*)d_in[15];
    const float* wg2 = (const float*)d_in[16];
    const float* wb2 = (const float*)d_in[17];
    const float* Ww2 = (const float*)d_in[18];
    const float* bw2 = (const float*)d_in[19];
    const float* Wc1 = (const float*)d_in[20];
    const float* cg1 = (const float*)d_in[21];
    const float* cb1 = (const float*)d_in[22];
    const float* Wc2 = (const float*)d_in[23];
    const float* cg2 = (const float*)d_in[24];
    const float* cb2 = (const float*)d_in[25];
    const float* Wc3 = (const float*)d_in[26];
    const float* bc3 = (const float*)d_in[27];
    const float* lng = (const float*)d_in[28];
    const float* lnb = (const float*)d_in[29];

    float* out = (float*)d_out;
    float* ws = (float*)d_ws;
    float* xq = ws;
    float* xk = xq + N * C;
    float* xv = xk + N * C;
    float* attn = xv + N * C;
    float* h2 = attn + N * C;             // N*128 floats
    int* knn = (int*)(h2 + N * 2 * C);    // N*16 ints

    qkv_kernel<<<256, 256, 0, stream>>>(feats, Wq, bq, Wk, bk, Wv, bv, xq, xk,
                                        xv);
    knn_kernel<<<2048, 256, 0, stream>>>((const int4*)indices, knn);
    attn_kernel<<<512, 256, 0, stream>>>((const int4*)indices, knn, xq, xk,
                                         xv, Wp1, pg, pb, Wp2, bp2, wg1, wb1,
                                         Ww1, wg2, wb2, Ww2, bw2, attn);
    head1_kernel<<<512, 256, 0, stream>>>(feats, attn, Wc1, cg1, cb1, Wc2,
                                          cg2, cb2, h2);
    head2_kernel<<<512, 256, 0, stream>>>(h2, Wc3, bc3, lng, lnb, out);
}